// Round 13
// baseline (190.726 us; speedup 1.0000x reference)
//
#include <hip/hip_runtime.h>
#include <cstddef>

// Problem constants (from reference)
#define BB 64
#define NN 207
#define KK 32
#define CC 8
#define DIN 64
#define DOUT 64
#define TILE 8               // n-positions per block; 128-thread blocks keep 8 pos/thread
#define THREADS 128          // 2 waves/block -> 1664 blocks = 6.5 independent ctx/CU
#define NT ((NN + TILE - 1) / TILE)   // 26 tiles along N -> 26 x 64 = 1664 blocks
#define MPAD 68              // mean row stride: phase-2 class rows 4 banks apart

__device__ __forceinline__ float fast_tanh(float v) {
    // tanh(v) = 1 - 2/(exp(2v)+1); ~1e-6 rel err, saturates correctly.
    float e = __expf(2.0f * v);
    return 1.0f - 2.0f * __builtin_amdgcn_rcpf(e + 1.0f);
}

// ---- kernel 0: W[C][DOUT][DIN] -> Wt[C][DIN][DOUT] (one class per block) ----
__global__ __launch_bounds__(256) void transpose_W_kernel(
    const float* __restrict__ W, float* __restrict__ Wt)
{
    __shared__ float t[DIN * (DOUT + 1)];   // +1 pad: conflict-free transpose
    const int c   = blockIdx.x;
    const int tid = threadIdx.x;
    const float* __restrict__ Wc  = W  + (size_t)c * DOUT * DIN;
    float* __restrict__       Wtc = Wt + (size_t)c * DIN * DOUT;
    #pragma unroll
    for (int r = 0; r < 16; ++r) {
        const int i = r * 256 + tid;        // i = o*DIN + d  (coalesced read)
        const int o = i >> 6, d = i & 63;
        t[d * (DOUT + 1) + o] = Wc[i];
    }
    __syncthreads();
    #pragma unroll
    for (int r = 0; r < 16; ++r) {
        const int i = r * 256 + tid;        // i = d*DOUT + o (coalesced write)
        const int d = i >> 6, o = i & 63;
        Wtc[i] = t[d * (DOUT + 1) + o];
    }
}

// ---- phase-1 helpers: static 2-buffer software pipeline (rule #20 safe) ----
__device__ __forceinline__ void pf8(float4 (&buf)[8],
                                    const float* __restrict__ xp, int g) {
    #pragma unroll
    for (int j = 0; j < 8; ++j)
        buf[j] = *(const float4*)(xp + (size_t)(g * 8 + j) * DIN);
}
__device__ __forceinline__ void cb8(float4 (&acc)[CC], const float4 (&buf)[8],
                                    const int* idx_row, int g) {
    #pragma unroll
    for (int j = 0; j < 8; ++j) {
        const int ca = idx_row[g * 8 + j];
        #pragma unroll
        for (int cc_ = 0; cc_ < CC; ++cc_) {
            const float mf = (ca == cc_) ? 1.0f : 0.0f;  // 1 cmp/sel + 4 fma per class
            acc[cc_].x = fmaf(mf, buf[j].x, acc[cc_].x);
            acc[cc_].y = fmaf(mf, buf[j].y, acc[cc_].y);
            acc[cc_].z = fmaf(mf, buf[j].z, acc[cc_].z);
            acc[cc_].w = fmaf(mf, buf[j].w, acc[cc_].w);
        }
    }
}

// ---- phase-2 helpers ----
__device__ __forceinline__ void wload(float4 (&w)[4],
                                      const float* __restrict__ Wtc, int dc) {
    #pragma unroll
    for (int j = 0; j < 4; ++j)
        w[j] = *(const float4*)(Wtc + (size_t)(dc * 4 + j) * DOUT);
}
__device__ __forceinline__ void wcompute(float4 (&acc2)[8], const float4 (&w)[4],
                                         const float* mean_base, int dc) {
    // mean_base = &mean_s[c * MPAD], stride per pos = CC*MPAD
    #pragma unroll
    for (int pp = 0; pp < 8; ++pp) {
        const float4 m = *(const float4*)(mean_base + (size_t)pp * CC * MPAD + dc * 4);
        acc2[pp].x = fmaf(m.x, w[0].x, acc2[pp].x);
        acc2[pp].y = fmaf(m.x, w[0].y, acc2[pp].y);
        acc2[pp].z = fmaf(m.x, w[0].z, acc2[pp].z);
        acc2[pp].w = fmaf(m.x, w[0].w, acc2[pp].w);
        acc2[pp].x = fmaf(m.y, w[1].x, acc2[pp].x);
        acc2[pp].y = fmaf(m.y, w[1].y, acc2[pp].y);
        acc2[pp].z = fmaf(m.y, w[1].z, acc2[pp].z);
        acc2[pp].w = fmaf(m.y, w[1].w, acc2[pp].w);
        acc2[pp].x = fmaf(m.z, w[2].x, acc2[pp].x);
        acc2[pp].y = fmaf(m.z, w[2].y, acc2[pp].y);
        acc2[pp].z = fmaf(m.z, w[2].z, acc2[pp].z);
        acc2[pp].w = fmaf(m.z, w[2].w, acc2[pp].w);
        acc2[pp].x = fmaf(m.w, w[3].x, acc2[pp].x);
        acc2[pp].y = fmaf(m.w, w[3].y, acc2[pp].y);
        acc2[pp].z = fmaf(m.w, w[3].z, acc2[pp].z);
        acc2[pp].w = fmaf(m.w, w[3].w, acc2[pp].w);
    }
}

// ---- main kernel ----
// TILE=8, 128 threads: per-thread work is IDENTICAL to the round-0 structure
// (phase 1: one position x full K=32 float4 slice; phase 2: 8 positions per
// thread, 8 W-loads/pos). Only block granularity halves -> 1664 blocks =
// 6.5 independent contexts/CU (vs 3.25), desynchronizing the stall windows.
// __launch_bounds__(128, 4): VGPR budget 128 (no spill at measured ~88),
// matches the LDS cap (18.7 KB -> 8 blocks/CU).
template<bool USE_WT>
__global__ __launch_bounds__(THREADS, 4) void ordered_gcn_kernel(
    const int* __restrict__ idx,      // [B, N, K]
    const float* __restrict__ x,      // [B, N, K, DIN]
    const float* __restrict__ W,      // [C, DOUT, DIN]
    const float* __restrict__ Wt,     // [C, DIN, DOUT] (in d_ws)
    float* __restrict__ out)          // [B, N, C, DOUT]
{
    __shared__ int   idx_s[TILE * KK];          // 1 KB
    __shared__ float inv_s[TILE * CC];          // 256 B
    __shared__ float mean_s[TILE * CC * MPAD];  // 17408 B  (total ~18.7 KB)

    const int tid = threadIdx.x;
    const int b  = blockIdx.y;
    const int n0 = blockIdx.x * TILE;

    // ---- load idx tile: 256 ints, 2 per thread, coalesced ----
    #pragma unroll
    for (int r = 0; r < 2; ++r) {
        const int i = r * THREADS + tid;
        const int pq = i >> 5, k = i & 31;
        int n = n0 + pq; if (n > NN - 1) n = NN - 1;   // clamped rows never stored
        idx_s[i] = idx[((size_t)(b * NN + n)) * KK + k];
    }
    __syncthreads();

    // ---- per (pos, class) inverse clamped count (64 threads) ----
    if (tid < TILE * CC) {
        const int pp = tid >> 3, c = tid & 7;
        int cnt = 0;
        #pragma unroll
        for (int k = 0; k < KK; ++k) cnt += (idx_s[pp * KK + k] == c) ? 1 : 0;
        inv_s[tid] = 1.0f / (float)(cnt > 1 ? cnt : 1);
    }
    // (inv_s is consumed only after the next barrier)

    // ---- phase 1: class-bucketed float4 sums, 2-buffer pipelined loads ----
    const int p  = tid >> 4;          // 0..7
    const int d4 = (tid & 15) * 4;
    {
        int n = n0 + p; if (n > NN - 1) n = NN - 1;
        const float* __restrict__ xp = x + ((size_t)(b * NN + n)) * KK * DIN + d4;
        const int* idx_row = &idx_s[p * KK];

        float4 acc[CC];
        #pragma unroll
        for (int c = 0; c < CC; ++c) acc[c] = make_float4(0.f, 0.f, 0.f, 0.f);

        float4 va[8], vb[8];
        pf8(va, xp, 0);
        pf8(vb, xp, 1);            // 16 loads in flight
        cb8(acc, va, idx_row, 0);
        pf8(va, xp, 2);
        cb8(acc, vb, idx_row, 1);
        pf8(vb, xp, 3);
        cb8(acc, va, idx_row, 2);
        cb8(acc, vb, idx_row, 3);

        __syncthreads();   // inv_s ready for all threads

        #pragma unroll
        for (int cc_ = 0; cc_ < CC; ++cc_) {
            const float s = inv_s[p * CC + cc_];
            float4 m;
            m.x = acc[cc_].x * s; m.y = acc[cc_].y * s;
            m.z = acc[cc_].z * s; m.w = acc[cc_].w * s;
            *(float4*)(&mean_s[(p * CC + cc_) * MPAD + d4]) = m;
        }
    }
    __syncthreads();

    // ---- phase 2: out[p][c][o] = tanh(sum_d mean[p][c][d] * Wt[c][d][o]) ----
    // thread = (c = (tid>>4)&7, o0 = (tid&15)*4) -> all 8 positions (pp=0..7).
    // W loads 2-buffer pipelined; tail peeled.
    {
        const int c  = (tid >> 4) & 7;
        const int o0 = (tid & 15) * 4;

        float4 acc2[8];
        #pragma unroll
        for (int pp = 0; pp < 8; ++pp) acc2[pp] = make_float4(0.f, 0.f, 0.f, 0.f);

        if (USE_WT) {
            const float* __restrict__ Wtc = Wt + (size_t)c * DIN * DOUT + o0;
            const float* mean_base = &mean_s[c * MPAD];

            float4 wa[4], wb[4];
            wload(wa, Wtc, 0);
            #pragma unroll 1
            for (int dc = 0; dc < 14; dc += 2) {
                wload(wb, Wtc, dc + 1);               // issue next rows
                wcompute(acc2, wa, mean_base, dc);    // compute current
                wload(wa, Wtc, dc + 2);
                wcompute(acc2, wb, mean_base, dc + 1);
            }
            wload(wb, Wtc, 15);                        // peeled tail
            wcompute(acc2, wa, mean_base, 14);
            wcompute(acc2, wb, mean_base, 15);
        } else {
            // fallback: raw W layout (scattered within wave, works without d_ws)
            const float* __restrict__ Wc = W + (size_t)c * DOUT * DIN;
            #pragma unroll 1
            for (int dc = 0; dc < 16; ++dc) {
                float4 w[4];
                #pragma unroll
                for (int j = 0; j < 4; ++j)
                    w[j] = *(const float4*)(Wc + (size_t)(o0 + j) * DIN + dc * 4);
                #pragma unroll
                for (int pp = 0; pp < 8; ++pp) {
                    const float4 m = *(const float4*)(&mean_s[(pp * CC + c) * MPAD + dc * 4]);
                    float* a = (float*)&acc2[pp];
                    #pragma unroll
                    for (int j = 0; j < 4; ++j) {
                        a[j] = fmaf(m.x, w[j].x, a[j]);
                        a[j] = fmaf(m.y, w[j].y, a[j]);
                        a[j] = fmaf(m.z, w[j].z, a[j]);
                        a[j] = fmaf(m.w, w[j].w, a[j]);
                    }
                }
            }
        }

        #pragma unroll
        for (int pp = 0; pp < 8; ++pp) {
            const int nn = n0 + pp;
            if (nn < NN) {
                float4 r;
                r.x = fast_tanh(acc2[pp].x);
                r.y = fast_tanh(acc2[pp].y);
                r.z = fast_tanh(acc2[pp].z);
                r.w = fast_tanh(acc2[pp].w);
                *(float4*)(out + (((size_t)(b * NN + nn)) * CC + c) * DOUT + o0) = r;
            }
        }
    }
}

extern "C" void kernel_launch(void* const* d_in, const int* in_sizes, int n_in,
                              void* d_out, int out_size, void* d_ws, size_t ws_size,
                              hipStream_t stream) {
    const int*   idx = (const int*)d_in[0];    // clustered_index_topk [B,N,K] int32
    const float* x   = (const float*)d_in[1];  // weightedDinput_topk [B,N,K,DIN] f32
    const float* W   = (const float*)d_in[2];  // W [C,DOUT,DIN] f32
    float* out = (float*)d_out;                // [B,N,C,DOUT] f32
    float* Wt  = (float*)d_ws;                 // [C,DIN,DOUT] scratch
                                               // (ws poison fills are unconditional -> free)
    dim3 grid(NT, BB);   // 26 x 64 = 1664 blocks
    dim3 block(THREADS);
    const size_t wt_bytes = (size_t)CC * DIN * DOUT * sizeof(float);  // 128 KB
    if (ws_size >= wt_bytes) {
        transpose_W_kernel<<<dim3(CC), dim3(256), 0, stream>>>(W, Wt);
        ordered_gcn_kernel<true><<<grid, block, 0, stream>>>(idx, x, W, Wt, out);
    } else {
        ordered_gcn_kernel<false><<<grid, block, 0, stream>>>(idx, x, W, Wt, out);
    }
}

// Round 16
// 186.747 us; speedup vs baseline: 1.0213x; 1.0213x over previous
//
#include <hip/hip_runtime.h>
#include <cstddef>

// Problem constants (from reference)
#define BB 64
#define NN 207
#define KK 32
#define CC 8
#define DIN 64
#define DOUT 64
#define TILE 32              // n-positions per block: 16 pos/thread in phase 2
#define THREADS 256
#define NT ((NN + TILE - 1) / TILE)   // 7 tiles -> 7 x 64 = 448 blocks
#define MPAD 68              // mean row stride: phase-2 class rows 4 banks apart

__device__ __forceinline__ float fast_tanh(float v) {
    // tanh(v) = 1 - 2/(exp(2v)+1); ~1e-6 rel err, saturates correctly.
    float e = __expf(2.0f * v);
    return 1.0f - 2.0f * __builtin_amdgcn_rcpf(e + 1.0f);
}

// ---- kernel 0: W[C][DOUT][DIN] -> Wt[C][DIN][DOUT] (one class per block) ----
__global__ __launch_bounds__(256) void transpose_W_kernel(
    const float* __restrict__ W, float* __restrict__ Wt)
{
    __shared__ float t[DIN * (DOUT + 1)];   // +1 pad: conflict-free transpose
    const int c   = blockIdx.x;
    const int tid = threadIdx.x;
    const float* __restrict__ Wc  = W  + (size_t)c * DOUT * DIN;
    float* __restrict__       Wtc = Wt + (size_t)c * DIN * DOUT;
    #pragma unroll
    for (int r = 0; r < 16; ++r) {
        const int i = r * 256 + tid;        // i = o*DIN + d  (coalesced read)
        const int o = i >> 6, d = i & 63;
        t[d * (DOUT + 1) + o] = Wc[i];
    }
    __syncthreads();
    #pragma unroll
    for (int r = 0; r < 16; ++r) {
        const int i = r * 256 + tid;        // i = d*DOUT + o (coalesced write)
        const int d = i >> 6, o = i & 63;
        Wtc[i] = t[d * (DOUT + 1) + o];
    }
}

// ---- phase-1 helpers ----
__device__ __forceinline__ void pf8(float4 (&buf)[8],
                                    const float* __restrict__ xp, int g) {
    #pragma unroll
    for (int j = 0; j < 8; ++j)
        buf[j] = *(const float4*)(xp + (size_t)(g * 8 + j) * DIN);
}
__device__ __forceinline__ void cb8(float4 (&acc)[CC], const float4 (&buf)[8],
                                    const int* idx_row, int g) {
    #pragma unroll
    for (int j = 0; j < 8; ++j) {
        const int ca = idx_row[g * 8 + j];
        #pragma unroll
        for (int cc_ = 0; cc_ < CC; ++cc_) {
            const float mf = (ca == cc_) ? 1.0f : 0.0f;  // 1 cmp/sel + 4 fma per class
            acc[cc_].x = fmaf(mf, buf[j].x, acc[cc_].x);
            acc[cc_].y = fmaf(mf, buf[j].y, acc[cc_].y);
            acc[cc_].z = fmaf(mf, buf[j].z, acc[cc_].z);
            acc[cc_].w = fmaf(mf, buf[j].w, acc[cc_].w);
        }
    }
}

// ---- phase-2 helpers: 16 positions per thread ----
__device__ __forceinline__ void wload(float4 (&w)[4],
                                      const float* __restrict__ Wtc, int dc) {
    #pragma unroll
    for (int j = 0; j < 4; ++j)
        w[j] = *(const float4*)(Wtc + (size_t)(dc * 4 + j) * DOUT);
}
__device__ __forceinline__ void wcompute16(float4 (&acc2)[16], const float4 (&w)[4],
                                           const float* mean_base, int dc) {
    // mean_base = &mean_s[(ph*16*CC + c) * MPAD], stride per pos = CC*MPAD
    #pragma unroll
    for (int pp = 0; pp < 16; ++pp) {
        const float4 m = *(const float4*)(mean_base + (size_t)pp * CC * MPAD + dc * 4);
        acc2[pp].x = fmaf(m.x, w[0].x, acc2[pp].x);
        acc2[pp].y = fmaf(m.x, w[0].y, acc2[pp].y);
        acc2[pp].z = fmaf(m.x, w[0].z, acc2[pp].z);
        acc2[pp].w = fmaf(m.x, w[0].w, acc2[pp].w);
        acc2[pp].x = fmaf(m.y, w[1].x, acc2[pp].x);
        acc2[pp].y = fmaf(m.y, w[1].y, acc2[pp].y);
        acc2[pp].z = fmaf(m.y, w[1].z, acc2[pp].z);
        acc2[pp].w = fmaf(m.y, w[1].w, acc2[pp].w);
        acc2[pp].x = fmaf(m.z, w[2].x, acc2[pp].x);
        acc2[pp].y = fmaf(m.z, w[2].y, acc2[pp].y);
        acc2[pp].z = fmaf(m.z, w[2].z, acc2[pp].z);
        acc2[pp].w = fmaf(m.z, w[2].w, acc2[pp].w);
        acc2[pp].x = fmaf(m.w, w[3].x, acc2[pp].x);
        acc2[pp].y = fmaf(m.w, w[3].y, acc2[pp].y);
        acc2[pp].z = fmaf(m.w, w[3].z, acc2[pp].z);
        acc2[pp].w = fmaf(m.w, w[3].w, acc2[pp].w);
    }
}

// ---- main kernel ----
// TILE=32, 256 threads: phase 1 -> each thread owns TWO positions (p, p+16);
// phase 2 -> 16 positions/thread (2x the proven-best W-amortization, the one
// knob that has consistently moved perf: 4pos=76us, 8pos=63us).
// LDS ~74.7 KB -> 2 blocks/CU; grid 448. __launch_bounds__(256,2): 256-VGPR
// budget so the ~140 live regs do NOT spill (rounds 6/13 trap).
template<bool USE_WT>
__global__ __launch_bounds__(THREADS, 2) void ordered_gcn_kernel(
    const int* __restrict__ idx,      // [B, N, K]
    const float* __restrict__ x,      // [B, N, K, DIN]
    const float* __restrict__ W,      // [C, DOUT, DIN]
    const float* __restrict__ Wt,     // [C, DIN, DOUT] (in d_ws)
    float* __restrict__ out)          // [B, N, C, DOUT]
{
    __shared__ int   idx_s[TILE * KK];          // 4 KB
    __shared__ float inv_s[TILE * CC];          // 1 KB
    __shared__ float mean_s[TILE * CC * MPAD];  // 69632 B  (total ~74.7 KB)

    const int tid = threadIdx.x;
    const int b  = blockIdx.y;
    const int n0 = blockIdx.x * TILE;

    // ---- load idx tile: 1024 ints, 4 per thread, coalesced ----
    #pragma unroll
    for (int r = 0; r < 4; ++r) {
        const int i = r * THREADS + tid;
        const int pq = i >> 5, k = i & 31;
        int n = n0 + pq; if (n > NN - 1) n = NN - 1;   // clamped rows never stored
        idx_s[i] = idx[((size_t)(b * NN + n)) * KK + k];
    }
    __syncthreads();

    // ---- per (pos, class) inverse clamped count (all 256 threads) ----
    {
        const int pp = tid >> 3, c = tid & 7;
        int cnt = 0;
        #pragma unroll
        for (int k = 0; k < KK; ++k) cnt += (idx_s[pp * KK + k] == c) ? 1 : 0;
        inv_s[tid] = 1.0f / (float)(cnt > 1 ? cnt : 1);
    }
    // (inv_s is consumed only after the next barrier)

    // ---- phase 1: class-bucketed float4 sums for TWO positions per thread ----
    // 16 loads in flight per batch (8 per position); same coalescing as before.
    const int p  = tid >> 4;          // 0..15  (positions p and p+16)
    const int d4 = (tid & 15) * 4;
    {
        int na = n0 + p;      if (na > NN - 1) na = NN - 1;
        int nb = n0 + p + 16; if (nb > NN - 1) nb = NN - 1;
        const float* __restrict__ xpa = x + ((size_t)(b * NN + na)) * KK * DIN + d4;
        const float* __restrict__ xpb = x + ((size_t)(b * NN + nb)) * KK * DIN + d4;
        const int* idx_row_a = &idx_s[p * KK];
        const int* idx_row_b = &idx_s[(p + 16) * KK];

        float4 acc0[CC], acc1[CC];
        #pragma unroll
        for (int c = 0; c < CC; ++c) {
            acc0[c] = make_float4(0.f, 0.f, 0.f, 0.f);
            acc1[c] = make_float4(0.f, 0.f, 0.f, 0.f);
        }

        #pragma unroll 1   // 16 loads issued per batch before any compute
        for (int g = 0; g < 4; ++g) {
            float4 va[8], vb[8];
            pf8(va, xpa, g);
            pf8(vb, xpb, g);
            cb8(acc0, va, idx_row_a, g);
            cb8(acc1, vb, idx_row_b, g);
        }

        __syncthreads();   // inv_s ready for all threads

        #pragma unroll
        for (int cc_ = 0; cc_ < CC; ++cc_) {
            const float s0 = inv_s[p * CC + cc_];
            const float s1 = inv_s[(p + 16) * CC + cc_];
            float4 m0, m1;
            m0.x = acc0[cc_].x * s0; m0.y = acc0[cc_].y * s0;
            m0.z = acc0[cc_].z * s0; m0.w = acc0[cc_].w * s0;
            m1.x = acc1[cc_].x * s1; m1.y = acc1[cc_].y * s1;
            m1.z = acc1[cc_].z * s1; m1.w = acc1[cc_].w * s1;
            *(float4*)(&mean_s[(p * CC + cc_) * MPAD + d4]) = m0;
            *(float4*)(&mean_s[((p + 16) * CC + cc_) * MPAD + d4]) = m1;
        }
    }
    __syncthreads();

    // ---- phase 2: out[p][c][o] = tanh(sum_d mean[p][c][d] * Wt[c][d][o]) ----
    // thread = (ph = tid>>7 -> pos 16ph..16ph+15, c = (tid>>4)&7, o0 = (tid&15)*4).
    // 16 positions share every W-load (2x round-0's amortization).
    {
        const int ph = tid >> 7;
        const int c  = (tid >> 4) & 7;
        const int o0 = (tid & 15) * 4;

        float4 acc2[16];
        #pragma unroll
        for (int pp = 0; pp < 16; ++pp) acc2[pp] = make_float4(0.f, 0.f, 0.f, 0.f);

        if (USE_WT) {
            const float* __restrict__ Wtc = Wt + (size_t)c * DIN * DOUT + o0;
            const float* mean_base = &mean_s[(ph * 16 * CC + c) * MPAD];

            float4 wa[4], wb[4];
            wload(wa, Wtc, 0);
            #pragma unroll 1
            for (int dc = 0; dc < 14; dc += 2) {
                wload(wb, Wtc, dc + 1);                 // issue next rows
                wcompute16(acc2, wa, mean_base, dc);    // compute current
                wload(wa, Wtc, dc + 2);
                wcompute16(acc2, wb, mean_base, dc + 1);
            }
            wload(wb, Wtc, 15);                          // peeled tail
            wcompute16(acc2, wa, mean_base, 14);
            wcompute16(acc2, wb, mean_base, 15);
        } else {
            // fallback: raw W layout (scattered within wave, works without d_ws)
            const float* __restrict__ Wc = W + (size_t)c * DOUT * DIN;
            #pragma unroll 1
            for (int dc = 0; dc < 16; ++dc) {
                float4 w[4];
                #pragma unroll
                for (int j = 0; j < 4; ++j)
                    w[j] = *(const float4*)(Wc + (size_t)(o0 + j) * DIN + dc * 4);
                #pragma unroll
                for (int pp = 0; pp < 16; ++pp) {
                    const int pq = ph * 16 + pp;
                    const float4 m = *(const float4*)(&mean_s[(pq * CC + c) * MPAD + dc * 4]);
                    float* a = (float*)&acc2[pp];
                    #pragma unroll
                    for (int j = 0; j < 4; ++j) {
                        a[j] = fmaf(m.x, w[j].x, a[j]);
                        a[j] = fmaf(m.y, w[j].y, a[j]);
                        a[j] = fmaf(m.z, w[j].z, a[j]);
                        a[j] = fmaf(m.w, w[j].w, a[j]);
                    }
                }
            }
        }

        #pragma unroll
        for (int pp = 0; pp < 16; ++pp) {
            const int pq = ph * 16 + pp;
            const int nn = n0 + pq;
            if (nn < NN) {
                float4 r;
                r.x = fast_tanh(acc2[pp].x);
                r.y = fast_tanh(acc2[pp].y);
                r.z = fast_tanh(acc2[pp].z);
                r.w = fast_tanh(acc2[pp].w);
                *(float4*)(out + (((size_t)(b * NN + nn)) * CC + c) * DOUT + o0) = r;
            }
        }
    }
}

extern "C" void kernel_launch(void* const* d_in, const int* in_sizes, int n_in,
                              void* d_out, int out_size, void* d_ws, size_t ws_size,
                              hipStream_t stream) {
    const int*   idx = (const int*)d_in[0];    // clustered_index_topk [B,N,K] int32
    const float* x   = (const float*)d_in[1];  // weightedDinput_topk [B,N,K,DIN] f32
    const float* W   = (const float*)d_in[2];  // W [C,DOUT,DIN] f32
    float* out = (float*)d_out;                // [B,N,C,DOUT] f32
    float* Wt  = (float*)d_ws;                 // [C,DIN,DOUT] scratch
                                               // (ws poison fills are unconditional -> free)
    dim3 grid(NT, BB);   // 7 x 64 = 448 blocks
    dim3 block(THREADS);
    const size_t wt_bytes = (size_t)CC * DIN * DOUT * sizeof(float);  // 128 KB
    if (ws_size >= wt_bytes) {
        transpose_W_kernel<<<dim3(CC), dim3(256), 0, stream>>>(W, Wt);
        ordered_gcn_kernel<true><<<grid, block, 0, stream>>>(idx, x, W, Wt, out);
    } else {
        ordered_gcn_kernel<false><<<grid, block, 0, stream>>>(idx, x, W, Wt, out);
    }
}